// Round 1
// baseline (173.042 us; speedup 1.0000x reference)
//
#include <hip/hip_runtime.h>

// Problem constants (fixed by setup_inputs)
#define B_DIM 8192
#define C_DIM 10000
#define C4    2500      // C_DIM / 4 (float4 groups)
#define RCHUNK 128      // rows per column-partial chunk
#define NCHUNK 64       // B_DIM / RCHUNK

// K1: partial column exp-sums. Grid (ceil(C4/256), NCHUNK), block 256.
// ps4[chunk*C4 + col4] = sum over RCHUNK rows of exp(x) per column (x4 lanes).
__global__ void col_partial_kernel(const float4* __restrict__ x4,
                                   float4* __restrict__ ps4) {
    int col4 = blockIdx.x * blockDim.x + threadIdx.x;
    if (col4 >= C4) return;
    int row0 = blockIdx.y * RCHUNK;
    const float4* p = x4 + (size_t)row0 * C4 + col4;
    float4 s = make_float4(0.f, 0.f, 0.f, 0.f);
#pragma unroll 4
    for (int r = 0; r < RCHUNK; ++r) {
        float4 v = p[(size_t)r * C4];
        s.x += __expf(v.x);
        s.y += __expf(v.y);
        s.z += __expf(v.z);
        s.w += __expf(v.w);
    }
    ps4[(size_t)blockIdx.y * C4 + col4] = s;
}

// K2: colLSE = log(sum of chunk partials). Grid ceil(C4/256), block 256.
__global__ void col_finalize_kernel(const float4* __restrict__ ps4,
                                    float4* __restrict__ colLSE4) {
    int col4 = blockIdx.x * blockDim.x + threadIdx.x;
    if (col4 >= C4) return;
    float4 s = make_float4(0.f, 0.f, 0.f, 0.f);
    for (int c = 0; c < NCHUNK; ++c) {
        float4 v = ps4[(size_t)c * C4 + col4];
        s.x += v.x; s.y += v.y; s.z += v.z; s.w += v.w;
    }
    float4 o;
    o.x = __logf(s.x); o.y = __logf(s.y); o.z = __logf(s.z); o.w = __logf(s.w);
    colLSE4[col4] = o;
}

// K3: per-row main pass. Grid B_DIM, block 256.
// ce_part[i]   = rowLSE_i - x[i, t_i]
// incl_part[i] = sum_j D[t_i, j] * (x_ij - colLSE_j)
__global__ void row_main_kernel(const float4* __restrict__ x4,
                                const float4* __restrict__ dm4,
                                const int* __restrict__ target,
                                const float4* __restrict__ colLSE4,
                                float* __restrict__ ce_part,
                                float* __restrict__ incl_part) {
    const int i   = blockIdx.x;
    const int tid = threadIdx.x;
    const int t   = target[i];
    const float4* xrow = x4 + (size_t)i * C4;
    const float4* drow = dm4 + (size_t)t * C4;
    const int tg = t >> 2, tl = t & 3;

    __shared__ float s_xt;
    __shared__ float s_red[2][4];  // 4 waves per 256-thread block

    float sumExp = 0.f;
    float dacc   = 0.f;
    for (int g = tid; g < C4; g += blockDim.x) {
        float4 xv = xrow[g];
        float4 dv = drow[g];
        float4 cv = colLSE4[g];
        sumExp += __expf(xv.x) + __expf(xv.y) + __expf(xv.z) + __expf(xv.w);
        dacc += dv.x * (xv.x - cv.x) + dv.y * (xv.y - cv.y)
              + dv.z * (xv.z - cv.z) + dv.w * (xv.w - cv.w);
        if (g == tg) {
            float xt = (tl == 0) ? xv.x : (tl == 1) ? xv.y : (tl == 2) ? xv.z : xv.w;
            s_xt = xt;  // exactly one thread hits this
        }
    }
    // wave (64-lane) reduction
    for (int off = 32; off > 0; off >>= 1) {
        sumExp += __shfl_down(sumExp, off, 64);
        dacc   += __shfl_down(dacc,   off, 64);
    }
    const int wave = tid >> 6;
    if ((tid & 63) == 0) { s_red[0][wave] = sumExp; s_red[1][wave] = dacc; }
    __syncthreads();
    if (tid == 0) {
        float se = 0.f, da = 0.f;
        for (int w = 0; w < 4; ++w) { se += s_red[0][w]; da += s_red[1][w]; }
        ce_part[i]   = __logf(se) - s_xt;
        incl_part[i] = da;
    }
}

// K4: final scalar. One block, 256 threads, double accumulation.
__global__ void final_kernel(const float* __restrict__ ce_part,
                             const float* __restrict__ incl_part,
                             float* __restrict__ out) {
    __shared__ double sd[2][256];
    const int tid = threadIdx.x;
    double ce = 0.0, incl = 0.0;
    for (int i = tid; i < B_DIM; i += 256) {
        ce   += (double)ce_part[i];
        incl += (double)incl_part[i];
    }
    sd[0][tid] = ce; sd[1][tid] = incl;
    __syncthreads();
    for (int s = 128; s > 0; s >>= 1) {
        if (tid < s) { sd[0][tid] += sd[0][tid + s]; sd[1][tid] += sd[1][tid + s]; }
        __syncthreads();
    }
    if (tid == 0) {
        double ce_mean = sd[0][0] / (double)B_DIM;
        double reg = -0.5 * sd[1][0] / ((double)C_DIM * (double)B_DIM);
        out[0] = (float)(ce_mean + reg);
    }
}

extern "C" void kernel_launch(void* const* d_in, const int* in_sizes, int n_in,
                              void* d_out, int out_size, void* d_ws, size_t ws_size,
                              hipStream_t stream) {
    const float* x  = (const float*)d_in[0];   // [B, C] f32
    const float* dm = (const float*)d_in[1];   // [C, C] f32
    const int* target = (const int*)d_in[2];   // [B] int
    float* out = (float*)d_out;

    // workspace layout (all 16B aligned)
    char* ws = (char*)d_ws;
    float4* ps4      = (float4*)ws;                              // NCHUNK*C4*16 = 2,560,000 B
    float4* colLSE4  = (float4*)(ws + (size_t)NCHUNK * C4 * 16); // 40,000 B
    char*   ws2      = ws + (size_t)NCHUNK * C4 * 16 + (size_t)C4 * 16;
    float*  ce_part  = (float*)ws2;                              // 32,768 B
    float*  incl_part = (float*)(ws2 + B_DIM * sizeof(float));   // 32,768 B

    const int colBlocks = (C4 + 255) / 256;  // 10
    col_partial_kernel<<<dim3(colBlocks, NCHUNK), 256, 0, stream>>>(
        (const float4*)x, ps4);
    col_finalize_kernel<<<colBlocks, 256, 0, stream>>>(ps4, colLSE4);
    row_main_kernel<<<B_DIM, 256, 0, stream>>>(
        (const float4*)x, (const float4*)dm, target, colLSE4, ce_part, incl_part);
    final_kernel<<<1, 256, 0, stream>>>(ce_part, incl_part, out);
}

// Round 2
// 126.875 us; speedup vs baseline: 1.3639x; 1.3639x over previous
//
#include <hip/hip_runtime.h>

#define B_DIM 8192
#define C_DIM 10000
#define C4    2500      // C_DIM / 4 (float4 groups)
#define NT    10        // column tiles of 256 float4 = 1024 columns
#define TILE4 256
#define NCH2  8         // second-level column-reduce partials

// Fused main pass. Grid (NT, nchunk), block 256 (4 waves).
// Each block: column tile [tile*1024, ...) x row chunk [chunk*rowchunk, ...).
// Produces:
//   colExpPart[chunk][col4] : partial column sums of exp(x)
//   colDPart[chunk][col4]   : partial column sums of D[t_i, :]
//   rowPartExp[tile][row]   : partial row sums of exp(x)
//   rowPartDx[tile][row]    : partial row sums of D[t_i,:]*x[i,:]
//   xt[row]                 : x[i, t_i] (written by the unique covering block)
__global__ __launch_bounds__(256) void fused_main(
    const float4* __restrict__ x4, const float4* __restrict__ dm4,
    const int* __restrict__ target,
    float4* __restrict__ colExpPart, float4* __restrict__ colDPart,
    float* __restrict__ rowPartExp, float* __restrict__ rowPartDx,
    float* __restrict__ xt, int rowchunk) {
    const int tile  = blockIdx.x;
    const int chunk = blockIdx.y;
    const int tid   = threadIdx.x;
    const int lane  = tid & 63;
    const int wave  = tid >> 6;
    const int base4 = tile * TILE4;
    const int row0  = chunk * rowchunk;

    __shared__ int    s_t[256];
    __shared__ float4 sE[TILE4];
    __shared__ float4 sD[TILE4];

    for (int r = tid; r < rowchunk; r += 256) s_t[r] = target[row0 + r];
    __syncthreads();

    int  col4[4];
    bool valid[4];
    float4 accE[4], accD[4];
#pragma unroll
    for (int it = 0; it < 4; ++it) {
        col4[it]  = base4 + it * 64 + lane;
        valid[it] = col4[it] < C4;
        accE[it] = make_float4(0.f, 0.f, 0.f, 0.f);
        accD[it] = make_float4(0.f, 0.f, 0.f, 0.f);
    }

    for (int r = wave; r < rowchunk; r += 4) {
        const int row = row0 + r;
        const int t   = s_t[r];
        const float4* xrow = x4 + (size_t)row * C4;
        const float4* drow = dm4 + (size_t)t * C4;
        const int tq = t >> 2, tl = t & 3;
        float rowE = 0.f, rowDx = 0.f;
#pragma unroll
        for (int it = 0; it < 4; ++it) {
            if (!valid[it]) continue;
            float4 xv = xrow[col4[it]];
            float4 dv = drow[col4[it]];
            float ex = __expf(xv.x), ey = __expf(xv.y),
                  ez = __expf(xv.z), ew = __expf(xv.w);
            accE[it].x += ex; accE[it].y += ey; accE[it].z += ez; accE[it].w += ew;
            rowE += (ex + ey) + (ez + ew);
            accD[it].x += dv.x; accD[it].y += dv.y;
            accD[it].z += dv.z; accD[it].w += dv.w;
            rowDx += dv.x * xv.x + dv.y * xv.y + dv.z * xv.z + dv.w * xv.w;
            if (col4[it] == tq) {
                float v = (tl == 0) ? xv.x : (tl == 1) ? xv.y
                        : (tl == 2) ? xv.z : xv.w;
                xt[row] = v;
            }
        }
#pragma unroll
        for (int off = 32; off > 0; off >>= 1) {
            rowE  += __shfl_down(rowE, off, 64);
            rowDx += __shfl_down(rowDx, off, 64);
        }
        if (lane == 0) {
            rowPartExp[(size_t)tile * B_DIM + row] = rowE;
            rowPartDx [(size_t)tile * B_DIM + row] = rowDx;
        }
    }

    // Combine column partials across the 4 waves via LDS (deterministic).
    if (wave == 0) {
#pragma unroll
        for (int it = 0; it < 4; ++it) {
            sE[it * 64 + lane] = accE[it];
            sD[it * 64 + lane] = accD[it];
        }
    }
    __syncthreads();
    for (int w = 1; w < 4; ++w) {
        if (wave == w) {
#pragma unroll
            for (int it = 0; it < 4; ++it) {
                float4 e = sE[it * 64 + lane];
                float4 d = sD[it * 64 + lane];
                e.x += accE[it].x; e.y += accE[it].y;
                e.z += accE[it].z; e.w += accE[it].w;
                d.x += accD[it].x; d.y += accD[it].y;
                d.z += accD[it].z; d.w += accD[it].w;
                sE[it * 64 + lane] = e;
                sD[it * 64 + lane] = d;
            }
        }
        __syncthreads();
    }
    const int colg = base4 + tid;
    if (colg < C4) {
        colExpPart[(size_t)chunk * C4 + colg] = sE[tid];
        colDPart [(size_t)chunk * C4 + colg] = sD[tid];
    }
}

// Stage-1 column reduce: nchunk -> NCH2 partials. Grid (10, NCH2), block 256.
__global__ __launch_bounds__(256) void col_reduce1(
    const float4* __restrict__ colExpPart, const float4* __restrict__ colDPart,
    float4* __restrict__ colExp2, float4* __restrict__ colD2, int nchunk) {
    const int col4 = blockIdx.x * 256 + threadIdx.x;
    const int part = blockIdx.y;
    if (col4 >= C4) return;
    const int per = nchunk / NCH2;
    const int c0  = part * per;
    float4 se = make_float4(0.f, 0.f, 0.f, 0.f);
    float4 sd = make_float4(0.f, 0.f, 0.f, 0.f);
    for (int c = c0; c < c0 + per; ++c) {
        float4 e = colExpPart[(size_t)c * C4 + col4];
        float4 d = colDPart [(size_t)c * C4 + col4];
        se.x += e.x; se.y += e.y; se.z += e.z; se.w += e.w;
        sd.x += d.x; sd.y += d.y; sd.z += d.z; sd.w += d.w;
    }
    colExp2[(size_t)part * C4 + col4] = se;
    colD2 [(size_t)part * C4 + col4] = sd;
}

// Stage-2: colLSE_j = log(sum exp), term2 = sum_j S_j * colLSE_j. Grid 10x256.
__global__ __launch_bounds__(256) void col_finalize(
    const float4* __restrict__ colExp2, const float4* __restrict__ colD2,
    double* __restrict__ term2_part) {
    const int col4 = blockIdx.x * 256 + threadIdx.x;
    double t2 = 0.0;
    if (col4 < C4) {
        float4 se = make_float4(0.f, 0.f, 0.f, 0.f);
        float4 sd = make_float4(0.f, 0.f, 0.f, 0.f);
        for (int c = 0; c < NCH2; ++c) {
            float4 e = colExp2[(size_t)c * C4 + col4];
            float4 d = colD2 [(size_t)c * C4 + col4];
            se.x += e.x; se.y += e.y; se.z += e.z; se.w += e.w;
            sd.x += d.x; sd.y += d.y; sd.z += d.z; sd.w += d.w;
        }
        t2 = (double)sd.x * (double)__logf(se.x)
           + (double)sd.y * (double)__logf(se.y)
           + (double)sd.z * (double)__logf(se.z)
           + (double)sd.w * (double)__logf(se.w);
    }
    __shared__ double sdd[256];
    sdd[threadIdx.x] = t2;
    __syncthreads();
    for (int s = 128; s > 0; s >>= 1) {
        if (threadIdx.x < s) sdd[threadIdx.x] += sdd[threadIdx.x + s];
        __syncthreads();
    }
    if (threadIdx.x == 0) term2_part[blockIdx.x] = sdd[0];
}

// Row finalize: rowLSE, ce_i, dx_i; block-reduce in double. Grid 32x256.
__global__ __launch_bounds__(256) void row_finalize(
    const float* __restrict__ rowPartExp, const float* __restrict__ rowPartDx,
    const float* __restrict__ xt, double* __restrict__ rowRed) {
    const int i = blockIdx.x * 256 + threadIdx.x;  // < 8192 exactly
    float re = 0.f, rdx = 0.f;
#pragma unroll
    for (int t = 0; t < NT; ++t) {
        re  += rowPartExp[(size_t)t * B_DIM + i];
        rdx += rowPartDx [(size_t)t * B_DIM + i];
    }
    double ce = (double)(__logf(re) - xt[i]);
    double dx = (double)rdx;
    __shared__ double s0[256], s1[256];
    s0[threadIdx.x] = ce; s1[threadIdx.x] = dx;
    __syncthreads();
    for (int s = 128; s > 0; s >>= 1) {
        if (threadIdx.x < s) {
            s0[threadIdx.x] += s0[threadIdx.x + s];
            s1[threadIdx.x] += s1[threadIdx.x + s];
        }
        __syncthreads();
    }
    if (threadIdx.x == 0) {
        rowRed[blockIdx.x * 2]     = s0[0];
        rowRed[blockIdx.x * 2 + 1] = s1[0];
    }
}

__global__ void final_k(const double* __restrict__ rowRed,
                        const double* __restrict__ term2_part,
                        float* __restrict__ out) {
    if (threadIdx.x == 0) {
        double ce = 0.0, dx = 0.0, t2 = 0.0;
        for (int b = 0; b < 32; ++b) { ce += rowRed[2 * b]; dx += rowRed[2 * b + 1]; }
        for (int b = 0; b < NT; ++b) t2 += term2_part[b];
        double ce_mean = ce / (double)B_DIM;
        double reg = -0.5 * (dx - t2) / ((double)C_DIM * (double)B_DIM);
        out[0] = (float)(ce_mean + reg);
    }
}

extern "C" void kernel_launch(void* const* d_in, const int* in_sizes, int n_in,
                              void* d_out, int out_size, void* d_ws, size_t ws_size,
                              hipStream_t stream) {
    const float4* x4  = (const float4*)d_in[0];
    const float4* dm4 = (const float4*)d_in[1];
    const int* target = (const int*)d_in[2];
    float* out = (float*)d_out;

    // Pick nchunk (row chunks) to fit workspace; 128 preferred for occupancy.
    const size_t fixed = 2 * (size_t)NCH2 * C4 * 16      // colExp2/colD2
                       + 2 * (size_t)NT * B_DIM * 4      // rowPartExp/Dx
                       + (size_t)B_DIM * 4               // xt
                       + 256 + 1024;                     // term2/rowRed + pad
    int nchunk = 128;
    while (nchunk > 32 && 2 * (size_t)nchunk * C4 * 16 + fixed > ws_size)
        nchunk >>= 1;
    const int rowchunk = B_DIM / nchunk;

    char* p = (char*)d_ws;
    auto alloc = [&](size_t bytes) {
        void* r = (void*)p;
        p += (bytes + 15) & ~(size_t)15;
        return r;
    };
    float4* colExpPart = (float4*)alloc((size_t)nchunk * C4 * 16);
    float4* colDPart   = (float4*)alloc((size_t)nchunk * C4 * 16);
    float4* colExp2    = (float4*)alloc((size_t)NCH2 * C4 * 16);
    float4* colD2      = (float4*)alloc((size_t)NCH2 * C4 * 16);
    float*  rowPartExp = (float*)alloc((size_t)NT * B_DIM * 4);
    float*  rowPartDx  = (float*)alloc((size_t)NT * B_DIM * 4);
    float*  xt         = (float*)alloc((size_t)B_DIM * 4);
    double* term2_part = (double*)alloc(NT * 8);
    double* rowRed     = (double*)alloc(64 * 8);

    fused_main<<<dim3(NT, nchunk), 256, 0, stream>>>(
        x4, dm4, target, colExpPart, colDPart, rowPartExp, rowPartDx, xt,
        rowchunk);
    col_reduce1<<<dim3(10, NCH2), 256, 0, stream>>>(
        colExpPart, colDPart, colExp2, colD2, nchunk);
    col_finalize<<<10, 256, 0, stream>>>(colExp2, colD2, term2_part);
    row_finalize<<<32, 256, 0, stream>>>(rowPartExp, rowPartDx, xt, rowRed);
    final_k<<<1, 64, 0, stream>>>(rowRed, term2_part, out);
}

// Round 3
// 115.693 us; speedup vs baseline: 1.4957x; 1.0967x over previous
//
#include <hip/hip_runtime.h>

#define B_DIM 8192
#define C_DIM 10000
#define C4    2500      // C_DIM / 4 (float4 groups)
#define NT    10        // column tiles of 256 float4 = 1024 columns
#define TILE4 256
#define NCHUNK 128      // row chunks (rowchunk = 64)
#define ROWCHUNK (B_DIM / NCHUNK)
#define NCH2  32        // second-level column-reduce partials

typedef float v4f __attribute__((ext_vector_type(4)));

// Fused main pass. Grid (NT, NCHUNK), block 256 (4 waves).
// Produces:
//   colExpPart[chunk][col4] : partial column sums of exp(x)
//   colDPart[chunk][col4]   : partial column sums of D[t_i, :]
//   rowPartExp[tile][row]   : partial row sums of exp(x)
//   rowPartDx[tile][row]    : partial row sums of D[t_i,:]*x[i,:]
//   xt[row]                 : x[i, t_i]
__global__ __launch_bounds__(256) void fused_main(
    const v4f* __restrict__ x4, const v4f* __restrict__ dm4,
    const int* __restrict__ target,
    v4f* __restrict__ colExpPart, v4f* __restrict__ colDPart,
    float* __restrict__ rowPartExp, float* __restrict__ rowPartDx,
    float* __restrict__ xt) {
    const int tile  = blockIdx.x;
    const int chunk = blockIdx.y;
    const int tid   = threadIdx.x;
    const int lane  = tid & 63;
    const int wave  = tid >> 6;
    const int base4 = tile * TILE4;
    const int row0  = chunk * ROWCHUNK;

    __shared__ int s_t[ROWCHUNK];
    __shared__ v4f sE[TILE4];
    __shared__ v4f sD[TILE4];

    for (int r = tid; r < ROWCHUNK; r += 256) s_t[r] = target[row0 + r];
    __syncthreads();

    int  col4[4];
    bool valid[4];
    v4f accE[4], accD[4];
#pragma unroll
    for (int it = 0; it < 4; ++it) {
        col4[it]  = base4 + it * 64 + lane;
        valid[it] = col4[it] < C4;
        accE[it] = (v4f){0.f, 0.f, 0.f, 0.f};
        accD[it] = (v4f){0.f, 0.f, 0.f, 0.f};
    }

    for (int r = wave; r < ROWCHUNK; r += 4) {
        const int row = row0 + r;
        const int t   = s_t[r];
        const v4f* xrow = x4 + (size_t)row * C4;
        const v4f* drow = dm4 + (size_t)t * C4;
        const int tq = t >> 2, tl = t & 3;
        float rowE = 0.f, rowDx = 0.f;
#pragma unroll
        for (int it = 0; it < 4; ++it) {
            if (!valid[it]) continue;
            // x is streamed exactly once: non-temporal (evict-first) so the
            // L2/L3 stay reserved for reused D rows.
            v4f xv = __builtin_nontemporal_load(&xrow[col4[it]]);
            v4f dv = drow[col4[it]];   // cached: D rows repeat across batch
            float ex = __expf(xv.x), ey = __expf(xv.y),
                  ez = __expf(xv.z), ew = __expf(xv.w);
            accE[it].x += ex; accE[it].y += ey; accE[it].z += ez; accE[it].w += ew;
            rowE += (ex + ey) + (ez + ew);
            accD[it].x += dv.x; accD[it].y += dv.y;
            accD[it].z += dv.z; accD[it].w += dv.w;
            rowDx += dv.x * xv.x + dv.y * xv.y + dv.z * xv.z + dv.w * xv.w;
            if (col4[it] == tq) {
                float v = (tl == 0) ? xv.x : (tl == 1) ? xv.y
                        : (tl == 2) ? xv.z : xv.w;
                xt[row] = v;
            }
        }
#pragma unroll
        for (int off = 32; off > 0; off >>= 1) {
            rowE  += __shfl_down(rowE, off, 64);
            rowDx += __shfl_down(rowDx, off, 64);
        }
        if (lane == 0) {
            rowPartExp[(size_t)tile * B_DIM + row] = rowE;
            rowPartDx [(size_t)tile * B_DIM + row] = rowDx;
        }
    }

    // Combine column partials across the 4 waves via LDS (deterministic).
    if (wave == 0) {
#pragma unroll
        for (int it = 0; it < 4; ++it) {
            sE[it * 64 + lane] = accE[it];
            sD[it * 64 + lane] = accD[it];
        }
    }
    __syncthreads();
    for (int w = 1; w < 4; ++w) {
        if (wave == w) {
#pragma unroll
            for (int it = 0; it < 4; ++it) {
                sE[it * 64 + lane] += accE[it];
                sD[it * 64 + lane] += accD[it];
            }
        }
        __syncthreads();
    }
    const int colg = base4 + tid;
    if (colg < C4) {
        colExpPart[(size_t)chunk * C4 + colg] = sE[tid];
        colDPart [(size_t)chunk * C4 + colg] = sD[tid];
    }
}

// Stage-1 column reduce: NCHUNK -> NCH2 partials. Grid (10, NCH2), block 256.
__global__ __launch_bounds__(256) void col_reduce1(
    const v4f* __restrict__ colExpPart, const v4f* __restrict__ colDPart,
    v4f* __restrict__ colExp2, v4f* __restrict__ colD2) {
    const int col4 = blockIdx.x * 256 + threadIdx.x;
    const int part = blockIdx.y;
    if (col4 >= C4) return;
    const int per = NCHUNK / NCH2;
    const int c0  = part * per;
    v4f se = {0.f, 0.f, 0.f, 0.f};
    v4f sd = {0.f, 0.f, 0.f, 0.f};
    for (int c = c0; c < c0 + per; ++c) {
        se += __builtin_nontemporal_load(&colExpPart[(size_t)c * C4 + col4]);
        sd += __builtin_nontemporal_load(&colDPart [(size_t)c * C4 + col4]);
    }
    colExp2[(size_t)part * C4 + col4] = se;
    colD2 [(size_t)part * C4 + col4] = sd;
}

// Stage-2: colLSE_j = log(sum exp), term2 = sum_j S_j * colLSE_j. Grid 10x256.
__global__ __launch_bounds__(256) void col_finalize(
    const v4f* __restrict__ colExp2, const v4f* __restrict__ colD2,
    double* __restrict__ term2_part) {
    const int col4 = blockIdx.x * 256 + threadIdx.x;
    double t2 = 0.0;
    if (col4 < C4) {
        v4f se = {0.f, 0.f, 0.f, 0.f};
        v4f sd = {0.f, 0.f, 0.f, 0.f};
        for (int c = 0; c < NCH2; ++c) {
            se += colExp2[(size_t)c * C4 + col4];
            sd += colD2 [(size_t)c * C4 + col4];
        }
        t2 = (double)sd.x * (double)__logf(se.x)
           + (double)sd.y * (double)__logf(se.y)
           + (double)sd.z * (double)__logf(se.z)
           + (double)sd.w * (double)__logf(se.w);
    }
    __shared__ double sdd[256];
    sdd[threadIdx.x] = t2;
    __syncthreads();
    for (int s = 128; s > 0; s >>= 1) {
        if (threadIdx.x < s) sdd[threadIdx.x] += sdd[threadIdx.x + s];
        __syncthreads();
    }
    if (threadIdx.x == 0) term2_part[blockIdx.x] = sdd[0];
}

// Row finalize: rowLSE, ce_i, dx_i; block-reduce in double. Grid 32x256.
__global__ __launch_bounds__(256) void row_finalize(
    const float* __restrict__ rowPartExp, const float* __restrict__ rowPartDx,
    const float* __restrict__ xt, double* __restrict__ rowRed) {
    const int i = blockIdx.x * 256 + threadIdx.x;  // < 8192 exactly
    float re = 0.f, rdx = 0.f;
#pragma unroll
    for (int t = 0; t < NT; ++t) {
        re  += rowPartExp[(size_t)t * B_DIM + i];
        rdx += rowPartDx [(size_t)t * B_DIM + i];
    }
    double ce = (double)(__logf(re) - xt[i]);
    double dx = (double)rdx;
    __shared__ double s0[256], s1[256];
    s0[threadIdx.x] = ce; s1[threadIdx.x] = dx;
    __syncthreads();
    for (int s = 128; s > 0; s >>= 1) {
        if (threadIdx.x < s) {
            s0[threadIdx.x] += s0[threadIdx.x + s];
            s1[threadIdx.x] += s1[threadIdx.x + s];
        }
        __syncthreads();
    }
    if (threadIdx.x == 0) {
        rowRed[blockIdx.x * 2]     = s0[0];
        rowRed[blockIdx.x * 2 + 1] = s1[0];
    }
}

__global__ void final_k(const double* __restrict__ rowRed,
                        const double* __restrict__ term2_part,
                        float* __restrict__ out) {
    if (threadIdx.x == 0) {
        double ce = 0.0, dx = 0.0, t2 = 0.0;
        for (int b = 0; b < 32; ++b) { ce += rowRed[2 * b]; dx += rowRed[2 * b + 1]; }
        for (int b = 0; b < NT; ++b) t2 += term2_part[b];
        double ce_mean = ce / (double)B_DIM;
        double reg = -0.5 * (dx - t2) / ((double)C_DIM * (double)B_DIM);
        out[0] = (float)(ce_mean + reg);
    }
}

extern "C" void kernel_launch(void* const* d_in, const int* in_sizes, int n_in,
                              void* d_out, int out_size, void* d_ws, size_t ws_size,
                              hipStream_t stream) {
    const v4f* x4  = (const v4f*)d_in[0];
    const v4f* dm4 = (const v4f*)d_in[1];
    const int* target = (const int*)d_in[2];
    float* out = (float*)d_out;

    char* p = (char*)d_ws;
    auto alloc = [&](size_t bytes) {
        void* r = (void*)p;
        p += (bytes + 15) & ~(size_t)15;
        return r;
    };
    v4f*    colExpPart = (v4f*)alloc((size_t)NCHUNK * C4 * 16);
    v4f*    colDPart   = (v4f*)alloc((size_t)NCHUNK * C4 * 16);
    v4f*    colExp2    = (v4f*)alloc((size_t)NCH2 * C4 * 16);
    v4f*    colD2      = (v4f*)alloc((size_t)NCH2 * C4 * 16);
    float*  rowPartExp = (float*)alloc((size_t)NT * B_DIM * 4);
    float*  rowPartDx  = (float*)alloc((size_t)NT * B_DIM * 4);
    float*  xt         = (float*)alloc((size_t)B_DIM * 4);
    double* term2_part = (double*)alloc(NT * 8);
    double* rowRed     = (double*)alloc(64 * 8);

    fused_main<<<dim3(NT, NCHUNK), 256, 0, stream>>>(
        x4, dm4, target, colExpPart, colDPart, rowPartExp, rowPartDx, xt);
    col_reduce1<<<dim3(10, NCH2), 256, 0, stream>>>(
        colExpPart, colDPart, colExp2, colD2);
    col_finalize<<<10, 256, 0, stream>>>(colExp2, colD2, term2_part);
    row_finalize<<<32, 256, 0, stream>>>(rowPartExp, rowPartDx, xt, rowRed);
    final_k<<<1, 64, 0, stream>>>(rowRed, term2_part, out);
}